// Round 1
// baseline (212.262 us; speedup 1.0000x reference)
//
#include <hip/hip_runtime.h>
#include <hip/hip_bf16.h>

// ---------------------------------------------------------------------------
// transBlock / DropBlock fused dual-conv:
//   a = conv3x3(x, w_layer3); b = conv3x3(x, w_pre)
//   sel[n,h,w] = maxpool7x7(mask_u < gamma)        (1 -> use b, 0 -> use a)
//   out[n,c,h,w] = (sel ? b : a) * 50176/(50176 - sum(sel))
//
// Implemented as one implicit GEMM: M=50176 positions, N=512 (a|b channels),
// K=2304 (=256*9), bf16 MFMA 16x16x32, fp32 accumulate.
//
// ws layout:
//   [0,4)                     : int dropped-count (atomic)
//   [1024, 1024+50176)        : sel bytes
//   [65536, +29491200)        : x_t  bf16 [64][30][30][256]  (zero halo)
//   [65536+29491200, +2359296): wt   bf16 pre-swizzled B blocks
// total ~31.9 MB
// ---------------------------------------------------------------------------

typedef __bf16  bf16x8 __attribute__((ext_vector_type(8)));
typedef float   f32x4  __attribute__((ext_vector_type(4)));
typedef unsigned int u32;
typedef unsigned short u16;

#define XT_BYTES   29491200    // 64*30*30*256*2
#define XT_OFF     65536
#define WT_OFF     (65536 + 29491200)
#define SEL_OFF    1024
#define NPOS       50176       // 64*28*28

__device__ __forceinline__ u16 f2bf(float v) {
    u32 u = __float_as_uint(v);
    u32 r = (u + 0x7FFFu + ((u >> 16) & 1u)) >> 16;
    return (u16)r;
}

__device__ __forceinline__ void gll16(const void* g, void* l) {
    __builtin_amdgcn_global_load_lds(
        (const __attribute__((address_space(1))) u32*)g,
        (__attribute__((address_space(3))) u32*)l, 16, 0, 0);
}

// ---------------- kernel 0: mask + pooled(sel) + dropped count -------------
__global__ void mask_kernel(const float* __restrict__ u,
                            unsigned char* __restrict__ sel,
                            int* __restrict__ dropped) {
    int m = blockIdx.x * 256 + threadIdx.x;          // grid exact: 196*256
    int n = m / 784, rem = m % 784;
    int h = rem / 28, w = rem % 28;
    const float g = (float)(0.1 / 49.0);
    const float* un = u + n * 784;
    int p = 0;
    for (int dy = -3; dy <= 3; ++dy) {
        int hh = h + dy;
        if (hh < 0 || hh >= 28) continue;
        for (int dx = -3; dx <= 3; ++dx) {
            int ww = w + dx;
            if (ww < 0 || ww >= 28) continue;
            p |= (un[hh * 28 + ww] < g) ? 1 : 0;
        }
    }
    sel[m] = (unsigned char)p;
    unsigned long long b = __ballot(p);
    if ((threadIdx.x & 63) == 0) atomicAdd(dropped, __popcll(b));
}

// ---------------- kernel 1: x NCHW f32 -> padded NHWC bf16 -----------------
__global__ void xt_kernel(const float* __restrict__ x, u16* __restrict__ xt) {
    int nh = blockIdx.x;                              // 64*28
    int n = nh / 28, h = nh % 28;
    int c = threadIdx.x;                              // 256
    const float* src = x + ((size_t)(n * 256 + c) * 28 + h) * 28;
    u16* dst = xt + ((size_t)(n * 30 + h + 1) * 30 + 1) * 256 + c;
    #pragma unroll 4
    for (int w = 0; w < 28; ++w)
        dst[(size_t)w * 256] = f2bf(src[w]);
}

// ---------------- kernel 2: weights -> pre-swizzled B blocks ---------------
// wt block id = (kk*4 + cb)*4 + nb ; block = [row=o_local 0..127][slot 0..7][j 0..7]
// phys (row,slot) holds logical channels (slot ^ (row&7))*8 + j  (XOR bank swizzle)
__global__ void wt_kernel(const float* __restrict__ wl,
                          const float* __restrict__ wp,
                          u16* __restrict__ wt) {
    int gid = blockIdx.x * 256 + threadIdx.x;         // 4608*256 = 1179648 exact
    int inner = gid & 8191;
    int bi = gid >> 13;
    int nb = bi & 3, cb = (bi >> 2) & 3, kk = bi >> 4;
    int ky = kk / 3, kx = kk % 3;
    int row = inner >> 6, r2 = inner & 63;
    int slot = r2 >> 3, j = r2 & 7;
    int c = cb * 64 + ((slot ^ (row & 7)) << 3) + j;
    int o = nb * 128 + row;
    const float* wsrc = (o < 256) ? wl : wp;
    int oo = o & 255;
    wt[gid] = f2bf(wsrc[((oo * 256 + c) * 3 + ky) * 3 + kx]);
}

// ---------------- kernel 3: implicit-GEMM conv + select + scale ------------
__global__ __launch_bounds__(256, 2)
void conv_kernel(const char* __restrict__ xt,    // bf16 padded NHWC (bytes)
                 const char* __restrict__ wt,    // bf16 swizzled blocks (bytes)
                 const unsigned char* __restrict__ sel,
                 const int* __restrict__ dropped,
                 float* __restrict__ out) {
    __shared__ char smem[65536];
    const int tid = threadIdx.x;
    const int bid = blockIdx.x;
    const int bm = bid >> 2;                 // 392 M-tiles
    const int bn = bid & 3;                  // 4 N-tiles (0,1 -> a ; 2,3 -> b)
    const int lane = tid & 63, wave = tid >> 6;
    const int lane15 = lane & 15, grp = lane >> 4;
    const int wm = (wave >> 1) * 64, wn = (wave & 1) * 64;

    // --- A staging source bases (bytes), swizzle folded in ---
    long pb[4];
    {
        int swzA = ((tid & 7) ^ ((tid >> 3) & 7)) << 4;
        #pragma unroll
        for (int i = 0; i < 4; ++i) {
            int r = i * 32 + (tid >> 3);
            int m = bm * 128 + r;
            int n = m / 784, rem = m % 784;
            int h = rem / 28, w = rem % 28;
            pb[i] = (long)(((n * 30 + h + 1) * 30 + (w + 1)) * 512 + swzA);
        }
    }

    f32x4 acc[4][4];
    #pragma unroll
    for (int i = 0; i < 4; ++i)
        #pragma unroll
        for (int j = 0; j < 4; ++j)
            acc[i][j] = (f32x4){0.f, 0.f, 0.f, 0.f};

    // --- prologue: stage tile 0 into buffer 0 ---
    {
        char* dA = smem;
        char* dB = smem + 16384;
        const char* wsrc = wt + ((size_t)bn << 14);      // t=0
        long co = -15872;                                 // kk=0 (ky=-1,kx=-1), cb=0
        #pragma unroll
        for (int i = 0; i < 4; ++i) {
            gll16(xt + pb[i] + co, dA + ((i * 256 + tid) << 4));
            gll16(wsrc + ((i * 256 + tid) << 4), dB + ((i * 256 + tid) << 4));
        }
    }
    asm volatile("s_waitcnt vmcnt(0)" ::: "memory");
    __syncthreads();

    int cur = 0;
    for (int t = 0; t < 36; ++t) {
        // stage t+1 into buf[cur^1]
        if (t + 1 < 36) {
            int tn = t + 1;
            int kk = tn >> 2, cb = tn & 3;
            int kkoff = ((kk / 3) * 30 + (kk % 3)) * 512 - 15872;  // ((ky-1)*30+(kx-1))*512
            char* dA = smem + ((cur ^ 1) * 32768);
            char* dB = dA + 16384;
            const char* wsrc = wt + ((((size_t)tn << 2) + bn) << 14);
            long co = (long)kkoff + cb * 128;
            #pragma unroll
            for (int i = 0; i < 4; ++i) {
                gll16(xt + pb[i] + co, dA + ((i * 256 + tid) << 4));
                gll16(wsrc + ((i * 256 + tid) << 4), dB + ((i * 256 + tid) << 4));
            }
        }
        // compute on buf[cur]
        {
            const char* sA = smem + cur * 32768;
            const char* sB = sA + 16384;
            #pragma unroll
            for (int half = 0; half < 2; ++half) {
                bf16x8 av[4], bv[4];
                const int so = (((half << 2) + grp) ^ (lane15 & 7)) << 4;
                #pragma unroll
                for (int f = 0; f < 4; ++f) {
                    av[f] = *(const bf16x8*)(sA + ((wm + (f << 4) + lane15) << 7) + so);
                    bv[f] = *(const bf16x8*)(sB + ((wn + (f << 4) + lane15) << 7) + so);
                }
                #pragma unroll
                for (int i = 0; i < 4; ++i)
                    #pragma unroll
                    for (int j = 0; j < 4; ++j)
                        acc[i][j] = __builtin_amdgcn_mfma_f32_16x16x32_bf16(
                            av[i], bv[j], acc[i][j], 0, 0, 0);
            }
        }
        __syncthreads();   // drains vmcnt(0): staged buf[cur^1] complete
        cur ^= 1;
    }

    // --- epilogue: LDS transpose -> coalesced, predicated, scaled stores ---
    float scale = 50176.0f / (float)(50176 - *dropped);
    const int mg = bm * 128 + wm + lane;
    const int n = mg / 784, rem = mg % 784;
    const unsigned char selv = sel[mg];
    const bool want = (bn >= 2) ? (selv != 0) : (selv == 0);
    const size_t obase = (size_t)n * 200704 + rem;
    float* ep = (float*)smem + wave * 2080;   // per-wave [32][65] f32 scratch

    __syncthreads();   // all compute done before LDS reuse
    #pragma unroll
    for (int chunk = 0; chunk < 2; ++chunk) {
        #pragma unroll
        for (int fm = 0; fm < 4; ++fm)
            #pragma unroll
            for (int f2 = 0; f2 < 2; ++f2) {
                int fn = chunk * 2 + f2;
                int col = f2 * 16 + lane15;
                int mrow = fm * 16 + grp * 4;
                #pragma unroll
                for (int j = 0; j < 4; ++j)
                    ep[col * 65 + mrow + j] = acc[fm][fn][j];
            }
        __syncthreads();
        if (want) {
            #pragma unroll
            for (int col = 0; col < 32; ++col) {
                float v = ep[col * 65 + lane] * scale;
                int oc = bn * 128 + wn + chunk * 32 + col;
                int c = oc & 255;
                out[obase + (size_t)c * 784] = v;
            }
        }
        __syncthreads();
    }
}

// ---------------------------------------------------------------------------
extern "C" void kernel_launch(void* const* d_in, const int* in_sizes, int n_in,
                              void* d_out, int out_size, void* d_ws, size_t ws_size,
                              hipStream_t stream) {
    const float* x  = (const float*)d_in[0];
    const float* wl = (const float*)d_in[1];
    const float* wp = (const float*)d_in[2];
    const float* mu = (const float*)d_in[3];
    float* out = (float*)d_out;
    char* ws = (char*)d_ws;

    int* dropped = (int*)ws;
    unsigned char* sel = (unsigned char*)(ws + SEL_OFF);
    u16* xt = (u16*)(ws + XT_OFF);
    u16* wt = (u16*)(ws + WT_OFF);

    hipMemsetAsync(ws, 0, 4, stream);
    hipMemsetAsync(xt, 0, XT_BYTES, stream);

    mask_kernel<<<196, 256, 0, stream>>>(mu, sel, dropped);
    xt_kernel<<<1792, 256, 0, stream>>>(x, xt);
    wt_kernel<<<4608, 256, 0, stream>>>(wl, wp, wt);
    conv_kernel<<<1568, 256, 0, stream>>>((const char*)xt, (const char*)wt,
                                          sel, dropped, out);
}

// Round 4
// 176.761 us; speedup vs baseline: 1.2008x; 1.2008x over previous
//
#include <hip/hip_runtime.h>
#include <hip/hip_bf16.h>

// ---------------------------------------------------------------------------
// DropBlock fused dual-conv as implicit GEMM, 256^2 tile, counted-vmcnt
// 4-slot LDS rotation pipeline (T2 swizzle + T3/T4 counted vmcnt + T5 setprio).
//   M = 50176 positions, N = 512 (a|b out-channels), K = 2304 (256 ch x 9 taps)
//   K-step = 32 -> 72 steps; slot s = t & 3; stage t+3 while computing t.
// ws layout:
//   [0,4)        : int dropped-count (atomic)
//   [1024, +50176): sel bytes
//   [65536, +29491200): x_t bf16 [64][30][30][256] (zero halo, written fully)
//   [+2359296]   : wt bf16 pre-swizzled B blocks [72*2][256][4][8]
// ---------------------------------------------------------------------------

typedef __bf16  bf16x8 __attribute__((ext_vector_type(8)));
typedef float   f32x4  __attribute__((ext_vector_type(4)));
typedef unsigned int u32;
typedef unsigned short u16;

#define XT_BYTES   29491200    // 64*30*30*256*2
#define XT_OFF     65536
#define WT_OFF     (65536 + 29491200)
#define SEL_OFF    1024

__device__ __forceinline__ u16 f2bf(float v) {
    u32 u = __float_as_uint(v);
    u32 r = (u + 0x7FFFu + ((u >> 16) & 1u)) >> 16;
    return (u16)r;
}

__device__ __forceinline__ void gll16(const void* g, void* l) {
    __builtin_amdgcn_global_load_lds(
        (const __attribute__((address_space(1))) u32*)g,
        (__attribute__((address_space(3))) u32*)l, 16, 0, 0);
}

// ---------------- kernel 0: mask + pooled(sel) + dropped count -------------
__global__ void mask_kernel(const float* __restrict__ u,
                            unsigned char* __restrict__ sel,
                            int* __restrict__ dropped) {
    int m = blockIdx.x * 256 + threadIdx.x;          // 196*256 exact
    int n = m / 784, rem = m % 784;
    int h = rem / 28, w = rem % 28;
    const float g = (float)(0.1 / 49.0);
    const float* un = u + n * 784;
    int p = 0;
    for (int dy = -3; dy <= 3; ++dy) {
        int hh = h + dy;
        if (hh < 0 || hh >= 28) continue;
        for (int dx = -3; dx <= 3; ++dx) {
            int ww = w + dx;
            if (ww < 0 || ww >= 28) continue;
            p |= (un[hh * 28 + ww] < g) ? 1 : 0;
        }
    }
    sel[m] = (unsigned char)p;
    unsigned long long b = __ballot(p);
    if ((threadIdx.x & 63) == 0) atomicAdd(dropped, __popcll(b));
}

// ---------------- kernel 1: x NCHW f32 -> padded NHWC bf16 + halo zero -----
__global__ void xt_kernel(const float* __restrict__ x, u16* __restrict__ xt) {
    int nb = blockIdx.x;                              // 64*30
    int n = nb / 30, oh = nb % 30;
    int tid = threadIdx.x;                            // 256
    u16* row = xt + (size_t)(n * 30 + oh) * 30 * 256;
    if (oh == 0 || oh == 29) {                        // halo rows: full zero
        u32* r32 = (u32*)row;                         // 3840 u32
        #pragma unroll
        for (int i = 0; i < 15; ++i) r32[i * 256 + tid] = 0;
        return;
    }
    int h = oh - 1;
    row[tid] = 0;                                     // halo col 0
    row[29 * 256 + tid] = 0;                          // halo col 29
    const float* src = x + ((size_t)(n * 256 + tid) * 28 + h) * 28;
    float f[28];
    #pragma unroll
    for (int q = 0; q < 7; ++q) {
        float4 v = *(const float4*)(src + q * 4);
        f[q * 4 + 0] = v.x; f[q * 4 + 1] = v.y;
        f[q * 4 + 2] = v.z; f[q * 4 + 3] = v.w;
    }
    #pragma unroll
    for (int w = 0; w < 28; ++w)
        row[(1 + w) * 256 + tid] = f2bf(f[w]);
}

// ---------------- kernel 2: weights -> pre-swizzled B blocks ---------------
// block b = t*2 + bn (t = K-step 0..71, bn 0..1); block = [row 0..255][ps 0..3][j 0..7]
// phys slot ps holds logical channels ( ps ^ ((row>>1)&3) )*8 + j
__global__ void wt_kernel(const float* __restrict__ wl,
                          const float* __restrict__ wp,
                          u16* __restrict__ wt) {
    int gid = blockIdx.x * 256 + threadIdx.x;         // 4608*256 = 1179648 exact
    int inner = gid & 8191;
    int b = gid >> 13;
    int t = b >> 1, bn = b & 1;
    int kk = t >> 3;                                  // tap 0..8
    int row = inner >> 5, r2 = inner & 31;
    int ps = r2 >> 3, j = r2 & 7;
    int ls = ps ^ ((row >> 1) & 3);
    int c = (t & 7) * 32 + ls * 8 + j;
    const float* wsrc = bn ? wp : wl;
    wt[gid] = f2bf(wsrc[((size_t)row * 256 + c) * 9 + kk]);
}

// ---------------- kernel 3: implicit-GEMM conv + select + scale ------------
__global__ __launch_bounds__(512, 2)
void conv_kernel(const char* __restrict__ xt,    // bf16 padded NHWC (bytes)
                 const char* __restrict__ wt,    // bf16 swizzled blocks (bytes)
                 const unsigned char* __restrict__ sel,
                 const int* __restrict__ dropped,
                 float* __restrict__ out) {
    __shared__ char smem[131072];
    const int tid = threadIdx.x;
    // XCD-aware swizzle (bijective: 392 = 8*49)
    const int lb = (blockIdx.x & 7) * 49 + (blockIdx.x >> 3);
    const int bm = lb >> 1;                  // 196 M-tiles of 256 positions
    const int bn = lb & 1;                   // 0 -> a (w_layer3), 1 -> b (w_pre)
    const int lane = tid & 63, wave = tid >> 6;
    const int lane15 = lane & 15, grp = lane >> 4;
    const int wm = wave >> 2, wn = wave & 3; // per-wave 128 x 64 output

    // --- A staging source bases (bytes); source-side swizzle folded in ---
    // load l (0,1): row = l*128 + (tid>>2), phys_slot = tid&3
    long pbA[2];
    {
        int swz = ((tid & 3) ^ ((tid >> 3) & 3)) << 4;
        #pragma unroll
        for (int l = 0; l < 2; ++l) {
            int r = l * 128 + (tid >> 2);
            int m = bm * 256 + r;
            int n = m / 784, rem = m % 784;
            int h = rem / 28, w = rem % 28;
            pbA[l] = (long)(((n * 30 + h + 1) * 30 + (w + 1)) * 512 + swz);
        }
    }

    f32x4 acc[8][4];
    #pragma unroll
    for (int i = 0; i < 8; ++i)
        #pragma unroll
        for (int j = 0; j < 4; ++j)
            acc[i][j] = (f32x4){0.f, 0.f, 0.f, 0.f};

#define STAGE(T) {                                                          \
        int kk_ = (T) >> 3;                                                 \
        long ao_ = (long)(kk_ / 3) * 15360 + (long)(kk_ % 3) * 512 - 15872  \
                   + (long)(((T) & 7) * 64);                                \
        char* As_ = smem + (((T) & 3) << 14);                               \
        char* Bs_ = smem + 65536 + (((T) & 3) << 14);                       \
        const char* wb_ = wt + ((size_t)((T) * 2 + bn) << 14);              \
        gll16(xt + pbA[0] + ao_, As_ + (tid << 4));                         \
        gll16(xt + pbA[1] + ao_, As_ + 8192 + (tid << 4));                  \
        gll16(wb_ + (tid << 4), Bs_ + (tid << 4));                         \
        gll16(wb_ + 8192 + (tid << 4), Bs_ + 8192 + (tid << 4));            \
    }

#define COMPUTE(T) {                                                        \
        const char* As_ = smem + (((T) & 3) << 14);                         \
        const char* Bs_ = smem + 65536 + (((T) & 3) << 14);                 \
        const int so_ = (grp ^ ((lane15 >> 1) & 3)) << 4;                   \
        bf16x8 av[8], bv[4];                                                \
        _Pragma("unroll")                                                   \
        for (int fm = 0; fm < 8; ++fm)                                      \
            av[fm] = *(const bf16x8*)(As_ +                                 \
                      ((wm * 128 + fm * 16 + lane15) << 6) + so_);          \
        _Pragma("unroll")                                                   \
        for (int fn = 0; fn < 4; ++fn)                                      \
            bv[fn] = *(const bf16x8*)(Bs_ +                                 \
                      ((wn * 64 + fn * 16 + lane15) << 6) + so_);           \
        __builtin_amdgcn_s_setprio(1);                                      \
        _Pragma("unroll")                                                   \
        for (int fm = 0; fm < 8; ++fm)                                      \
            _Pragma("unroll")                                               \
            for (int fn = 0; fn < 4; ++fn)                                  \
                acc[fm][fn] = __builtin_amdgcn_mfma_f32_16x16x32_bf16(      \
                    av[fm], bv[fn], acc[fm][fn], 0, 0, 0);                  \
        __builtin_amdgcn_s_setprio(0);                                      \
    }

    // prologue: 3 steps in flight
    STAGE(0); STAGE(1); STAGE(2);

    for (int t = 0; t < 70; ++t) {
        if (t < 69) STAGE(t + 3);
        asm volatile("s_waitcnt vmcnt(8)" ::: "memory");
        asm volatile("s_barrier" ::: "memory");
        COMPUTE(t);
        asm volatile("s_barrier" ::: "memory");
    }
    asm volatile("s_waitcnt vmcnt(4)" ::: "memory");
    asm volatile("s_barrier" ::: "memory");
    COMPUTE(70);
    asm volatile("s_barrier" ::: "memory");
    asm volatile("s_waitcnt vmcnt(0)" ::: "memory");
    asm volatile("s_barrier" ::: "memory");
    COMPUTE(71);

    // --- epilogue: per-wave LDS transpose -> coalesced predicated stores ---
    float scale = 50176.0f / (float)(50176 - *dropped);
    float* ep = (float*)(smem + (wave << 14));   // private [32][65] f32
    __syncthreads();                              // all slot reads done
    #pragma unroll
    for (int rr = 0; rr < 4; ++rr) {
        const int r2 = rr & 1;        // fn pair (32 channels)
        const int mh = rr >> 1;       // m half (64 positions)
        #pragma unroll
        for (int fm2 = 0; fm2 < 4; ++fm2)
            #pragma unroll
            for (int f2 = 0; f2 < 2; ++f2)
                #pragma unroll
                for (int j = 0; j < 4; ++j)
                    ep[(f2 * 16 + lane15) * 65 + fm2 * 16 + grp * 4 + j] =
                        acc[mh * 4 + fm2][r2 * 2 + f2][j];
        __syncthreads();
        {
            int p = bm * 256 + wm * 128 + mh * 64 + lane;
            int n = p / 784, rem = p % 784;
            unsigned char sv = sel[p];
            bool want = bn ? (sv != 0) : (sv == 0);
            size_t ob = (size_t)n * 200704 + rem;
            if (want) {
                #pragma unroll
                for (int ch = 0; ch < 32; ++ch)
                    out[ob + (size_t)(wn * 64 + r2 * 32 + ch) * 784] =
                        ep[ch * 65 + lane] * scale;
            }
        }
        __syncthreads();
    }
#undef STAGE
#undef COMPUTE
}

// ---------------------------------------------------------------------------
extern "C" void kernel_launch(void* const* d_in, const int* in_sizes, int n_in,
                              void* d_out, int out_size, void* d_ws, size_t ws_size,
                              hipStream_t stream) {
    const float* x  = (const float*)d_in[0];
    const float* wl = (const float*)d_in[1];
    const float* wp = (const float*)d_in[2];
    const float* mu = (const float*)d_in[3];
    float* out = (float*)d_out;
    char* ws = (char*)d_ws;

    int* dropped = (int*)ws;
    unsigned char* sel = (unsigned char*)(ws + SEL_OFF);
    u16* xt = (u16*)(ws + XT_OFF);
    u16* wt = (u16*)(ws + WT_OFF);

    hipMemsetAsync(ws, 0, 4, stream);

    mask_kernel<<<196, 256, 0, stream>>>(mu, sel, dropped);
    xt_kernel<<<1920, 256, 0, stream>>>(x, xt);
    wt_kernel<<<4608, 256, 0, stream>>>(wl, wp, wt);
    conv_kernel<<<392, 512, 0, stream>>>((const char*)xt, (const char*)wt,
                                         sel, dropped, out);
}

// Round 8
// 162.926 us; speedup vs baseline: 1.3028x; 1.0849x over previous
//
#include <hip/hip_runtime.h>
#include <hip/hip_bf16.h>

// ---------------------------------------------------------------------------
// DropBlock fused dual-conv as implicit GEMM, 256^2 tile, BK=64,
// 4-phase interleave per K-tile with counted vmcnt (T2+T3+T4+T5).
//   M = 50176 positions, N = 512 (a|b out-channels), K = 2304 (256 ch x 9 taps)
//   36 K-tiles of 64; double-buffered LDS; stage order per tile: B0,B1,A0,A1.
// A-half staging matches phase read-sets (the round-5/6 race fix):
//   STG_A(0) -> LDS [0,16384)    = rows {0..63, 128..191}   (read by MH=0: both wm)
//   STG_A(1) -> LDS [16384,32768)= rows {64..127, 192..255} (read by MH=1)
// Wait ledger (per-wave, 2 loads per staged half, FIFO retirement):
//   prologue: stage tile0 (8), vmcnt(2)+bar  -> B0,B1,A0 retired; A1 in flight
//   P0 reads B + A[MH=0]; post-MFMA vmcnt(2) retires A1(t)
//   P1 reads A[MH=1]; P2 re-reads MH=0 (hi-k); P3 reads MH=1 (hi-k)
//   P3 post-MFMA vmcnt(2) retires B0',B1',A0' of t+1 (A1' stays in flight)
//   -> every ds_read covered by a prior vmcnt+barrier; never drain to 0 mid-loop.
// ws layout:
//   [0,4)        : int dropped-count (atomic)
//   [1024, +50176): sel bytes
//   [65536, +29491200): x_t bf16 [64][30][30][256] (zero halo, written fully)
//   [+2359296]   : wt bf16 pre-swizzled B blocks [36*2][256][8][8]
// ---------------------------------------------------------------------------

typedef __bf16  bf16x8 __attribute__((ext_vector_type(8)));
typedef float   f32x4  __attribute__((ext_vector_type(4)));
typedef unsigned int u32;
typedef unsigned short u16;

#define XT_OFF     65536
#define WT_OFF     (65536 + 29491200)
#define SEL_OFF    1024

__device__ __forceinline__ u16 f2bf(float v) {
    u32 u = __float_as_uint(v);
    u32 r = (u + 0x7FFFu + ((u >> 16) & 1u)) >> 16;
    return (u16)r;
}

__device__ __forceinline__ void gll16(const void* g, void* l) {
    __builtin_amdgcn_global_load_lds(
        (const __attribute__((address_space(1))) u32*)g,
        (__attribute__((address_space(3))) u32*)l, 16, 0, 0);
}

// ---------------- fused prep: xt transform + wt swizzle + mask -------------
__global__ void prep_kernel(const float* __restrict__ x,
                            const float* __restrict__ wl,
                            const float* __restrict__ wp,
                            const float* __restrict__ mu,
                            u16* __restrict__ xt, u16* __restrict__ wt,
                            unsigned char* __restrict__ sel,
                            int* __restrict__ dropped) {
    int b = blockIdx.x, tid = threadIdx.x;
    if (b < 1920) {                                   // ---- xt: 64*30 rows
        int n = b / 30, oh = b % 30;
        u16* row = xt + (size_t)(n * 30 + oh) * 30 * 256;
        if (oh == 0 || oh == 29) {                    // halo rows: full zero
            u32* r32 = (u32*)row;
            #pragma unroll
            for (int i = 0; i < 15; ++i) r32[i * 256 + tid] = 0;
            return;
        }
        int h = oh - 1;
        row[tid] = 0;
        row[29 * 256 + tid] = 0;
        const float* src = x + ((size_t)(n * 256 + tid) * 28 + h) * 28;
        float f[28];
        #pragma unroll
        for (int q = 0; q < 7; ++q) {
            float4 v = *(const float4*)(src + q * 4);
            f[q * 4 + 0] = v.x; f[q * 4 + 1] = v.y;
            f[q * 4 + 2] = v.z; f[q * 4 + 3] = v.w;
        }
        #pragma unroll
        for (int w = 0; w < 28; ++w)
            row[(1 + w) * 256 + tid] = f2bf(f[w]);
    } else if (b < 6528) {                            // ---- wt: pre-swizzled B
        // block bb = t*2 + bn (t 0..35); [row 0..255][ps 0..7][jj 0..7]
        // phys slot ps holds logical channels (ps ^ (row&7))*8 + jj
        int gid = (b - 1920) * 256 + tid;             // 4608*256 = 1179648
        int bb = gid >> 14;
        int e = gid & 16383;
        int t = bb >> 1, bnn = bb & 1;
        int kk = t >> 2;                              // tap 0..8
        int row = e >> 6, r2 = e & 63;
        int ps = r2 >> 3, jj = r2 & 7;
        int c = (t & 3) * 64 + ((ps ^ (row & 7)) << 3) + jj;
        const float* wsrc = bnn ? wp : wl;
        wt[gid] = f2bf(wsrc[((size_t)row * 256 + c) * 9 + kk]);
    } else {                                          // ---- mask + pooled sel
        int m = (b - 6528) * 256 + tid;               // 196*256 exact
        int n = m / 784, rem = m % 784;
        int h = rem / 28, w = rem % 28;
        const float g = (float)(0.1 / 49.0);
        const float* un = mu + n * 784;
        int p = 0;
        for (int dy = -3; dy <= 3; ++dy) {
            int hh = h + dy;
            if (hh < 0 || hh >= 28) continue;
            for (int dx = -3; dx <= 3; ++dx) {
                int ww = w + dx;
                if (ww < 0 || ww >= 28) continue;
                p |= (un[hh * 28 + ww] < g) ? 1 : 0;
            }
        }
        sel[m] = (unsigned char)p;
        unsigned long long bl = __ballot(p);
        if ((tid & 63) == 0) atomicAdd(dropped, __popcll(bl));
    }
}

// ---------------- implicit-GEMM conv + select + scale ----------------------
__global__ __launch_bounds__(512, 2)
void conv_kernel(const char* __restrict__ xt,    // bf16 padded NHWC (bytes)
                 const char* __restrict__ wt,    // bf16 swizzled blocks (bytes)
                 const unsigned char* __restrict__ sel,
                 const int* __restrict__ dropped,
                 float* __restrict__ out) {
    __shared__ char smem[131072];
    const int tid = threadIdx.x;
    // XCD-aware swizzle (bijective: 392 = 8*49)
    const int lb = (blockIdx.x & 7) * 49 + (blockIdx.x >> 3);
    const int bm = lb >> 1;                  // 196 M-tiles of 256 positions
    const int bn = lb & 1;                   // 0 -> a (w_layer3), 1 -> b (w_pre)
    const int lane = tid & 63, wave = tid >> 6;
    const int lane15 = lane & 15, grp = lane >> 4;
    const int wm = wave >> 2, wn = wave & 3; // per-wave 128 x 64 output

    // --- A staging source bases (bytes); source-side swizzle folded in ---
    // pbA[i]: rows i*64 + (tid>>3), phys slot = tid&7
    long pbA[4];
    {
        int swz = ((tid & 7) ^ ((tid >> 3) & 7)) << 4;
        #pragma unroll
        for (int i = 0; i < 4; ++i) {
            int r = i * 64 + (tid >> 3);
            int m = bm * 256 + r;
            int n = m / 784, rem = m % 784;
            int h = rem / 28, w = rem % 28;
            pbA[i] = (long)(((n * 30 + h + 1) * 30 + (w + 1)) * 512 + swz);
        }
    }

    f32x4 acc[8][4];
    #pragma unroll
    for (int i = 0; i < 8; ++i)
        #pragma unroll
        for (int j = 0; j < 4; ++j)
            acc[i][j] = (f32x4){0.f, 0.f, 0.f, 0.f};

    const int so0 = (grp ^ (lane15 & 7)) << 4;           // kh=0 read swizzle
    const int so1 = ((4 + grp) ^ (lane15 & 7)) << 4;     // kh=1
    // A LDS chunk order: [0]=rows0-63, [8192]=rows128-191,
    //                    [16384]=rows64-127, [24576]=rows192-255
    // row r = wm*128 + MH*64 + fm*16 + lane15 -> byte MH*16384 + wm*8192 + ...
    const int aro = wm * 8192 + (lane15 << 7);           // A byte base
    const int bro = 32768 + ((wn * 64 + lane15) << 7);   // B byte base

#define STG_B(H) {                                                          \
        gll16(wbn + (H)*16384 + (tid<<4), nb_ + 32768 + (H)*16384 + (tid<<4)); \
        gll16(wbn + (H)*16384 + 8192 + (tid<<4),                            \
              nb_ + 32768 + (H)*16384 + 8192 + (tid<<4));                   \
    }
// STG_A(H) stages the MH=H read-set: rows {H*64..H*64+63, 128+H*64..128+H*64+63}
#define STG_A(H) {                                                          \
        gll16(xt + pbA[(H)] + aon, nb_ + (H)*16384 + (tid<<4));             \
        gll16(xt + pbA[(H)+2] + aon, nb_ + (H)*16384 + 8192 + (tid<<4));    \
    }

#define PHASE(MH, SO, DOB, STG, WAITASM) {                                  \
        bf16x8 av[4];                                                       \
        _Pragma("unroll")                                                   \
        for (int fm = 0; fm < 4; ++fm)                                      \
            av[fm] = *(const bf16x8*)(cb_ + aro + (MH)*16384 + fm*2048 + (SO)); \
        if (DOB) {                                                          \
            _Pragma("unroll")                                               \
            for (int fn = 0; fn < 4; ++fn)                                  \
                bv[fn] = *(const bf16x8*)(cb_ + bro + fn*2048 + (SO));      \
        }                                                                   \
        STG;                                                                \
        asm volatile("s_barrier" ::: "memory");                             \
        asm volatile("s_waitcnt lgkmcnt(0)" ::: "memory");                  \
        __builtin_amdgcn_sched_barrier(0);                                  \
        __builtin_amdgcn_s_setprio(1);                                      \
        _Pragma("unroll")                                                   \
        for (int fm = 0; fm < 4; ++fm)                                      \
            _Pragma("unroll")                                               \
            for (int fn = 0; fn < 4; ++fn)                                  \
                acc[(MH)*4+fm][fn] = __builtin_amdgcn_mfma_f32_16x16x32_bf16( \
                    av[fm], bv[fn], acc[(MH)*4+fm][fn], 0, 0, 0);           \
        __builtin_amdgcn_s_setprio(0);                                      \
        WAITASM;                                                            \
        asm volatile("s_barrier" ::: "memory");                             \
    }

    // --- prologue: stage tile 0 (order B0,B1,A0,A1 = steady-state order) ---
    {
        char* nb_ = smem;
        const char* wbn = wt + (size_t)bn * 32768;
        const long aon = -15872;                       // t=0: kk=0, cb=0
        STG_B(0); STG_B(1); STG_A(0); STG_A(1);
    }
    // retire B0,B1,A0 of tile 0 (A1 stays in flight until P0's post-MFMA wait)
    asm volatile("s_waitcnt vmcnt(2)" ::: "memory");
    asm volatile("s_barrier" ::: "memory");

    bf16x8 bv[4];
    for (int t = 0; t < 35; ++t) {
        const char* cb_ = smem + (t & 1) * 65536;
        char* nb_ = smem + ((t + 1) & 1) * 65536;
        const int tn = t + 1;
        const int kkn = tn >> 2;
        const long aon = (long)(kkn / 3) * 15360 + (long)(kkn % 3) * 512
                         - 15872 + (long)((tn & 3) * 128);
        const char* wbn = wt + (size_t)(tn * 2 + bn) * 32768;
        PHASE(0, so0, true,  STG_B(0),
              asm volatile("s_waitcnt vmcnt(2)" ::: "memory"));  // retire A1(t)
        PHASE(1, so0, false, STG_B(1), ((void)0));
        PHASE(0, so1, true,  STG_A(0), ((void)0));
        PHASE(1, so1, false, STG_A(1),
              asm volatile("s_waitcnt vmcnt(2)" ::: "memory"));  // retire B0',B1',A0'
    }
    {   // t = 35: no staging
        const char* cb_ = smem + 65536;                // 35&1 = 1
        PHASE(0, so0, true,  ((void)0),
              asm volatile("s_waitcnt vmcnt(0)" ::: "memory"));  // retire A1(35)
        PHASE(1, so0, false, ((void)0), ((void)0));
        PHASE(0, so1, true,  ((void)0), ((void)0));
        PHASE(1, so1, false, ((void)0), ((void)0));
    }

    // --- epilogue: per-wave LDS transpose -> coalesced predicated stores ---
    float scale = 50176.0f / (float)(50176 - *dropped);
    float* ep = (float*)(smem + (wave << 14));   // private [32][65] f32
    __syncthreads();                              // all LDS reads done
    #pragma unroll
    for (int rr = 0; rr < 4; ++rr) {
        const int r2 = rr & 1;        // fn pair (32 channels)
        const int mh = rr >> 1;       // m half (64 positions)
        #pragma unroll
        for (int fm2 = 0; fm2 < 4; ++fm2)
            #pragma unroll
            for (int f2 = 0; f2 < 2; ++f2)
                #pragma unroll
                for (int j = 0; j < 4; ++j)
                    ep[(f2 * 16 + lane15) * 65 + fm2 * 16 + grp * 4 + j] =
                        acc[mh * 4 + fm2][r2 * 2 + f2][j];
        __syncthreads();
        {
            int p = bm * 256 + wm * 128 + mh * 64 + lane;
            int n = p / 784, rem = p % 784;
            unsigned char sv = sel[p];
            bool want = bn ? (sv != 0) : (sv == 0);
            size_t ob = (size_t)n * 200704 + rem;
            if (want) {
                #pragma unroll
                for (int ch = 0; ch < 32; ++ch)
                    out[ob + (size_t)(wn * 64 + r2 * 32 + ch) * 784] =
                        ep[ch * 65 + lane] * scale;
            }
        }
        __syncthreads();
    }
#undef STG_A
#undef STG_B
#undef PHASE
}

// ---------------------------------------------------------------------------
extern "C" void kernel_launch(void* const* d_in, const int* in_sizes, int n_in,
                              void* d_out, int out_size, void* d_ws, size_t ws_size,
                              hipStream_t stream) {
    const float* x  = (const float*)d_in[0];
    const float* wl = (const float*)d_in[1];
    const float* wp = (const float*)d_in[2];
    const float* mu = (const float*)d_in[3];
    float* out = (float*)d_out;
    char* ws = (char*)d_ws;

    int* dropped = (int*)ws;
    unsigned char* sel = (unsigned char*)(ws + SEL_OFF);
    u16* xt = (u16*)(ws + XT_OFF);
    u16* wt = (u16*)(ws + WT_OFF);

    hipMemsetAsync(ws, 0, 4, stream);

    prep_kernel<<<6724, 256, 0, stream>>>(x, wl, wp, mu, xt, wt, sel, dropped);
    conv_kernel<<<392, 512, 0, stream>>>((const char*)xt, (const char*)wt,
                                         sel, dropped, out);
}

// Round 9
// 158.893 us; speedup vs baseline: 1.3359x; 1.0254x over previous
//
#include <hip/hip_runtime.h>
#include <hip/hip_bf16.h>

// ---------------------------------------------------------------------------
// DropBlock fused dual-conv as implicit GEMM, 256^2 tile, BK=32,
// 4-slot LDS rotation (depth-3 prefetch) + register double-buffered fragments
// with counted lgkmcnt so LDS reads overlap the MFMA cluster (T2+T3+T4+T5).
//   M = 50176, N = 512 (a|b), K = 2304; 72 K-tiles of 32; 2 phases/tile.
// Per-wave ledger (4 gll16 ops/tile, FIFO; stage tile t+3 during tile t):
//   prologue: stage tiles 0,1,2 (12 ops); vmcnt(8) retires tile 0; barrier;
//             read av0/bv0 of tile 0.
//   P0(t): read av1(t); stage A0,B0(t+3); lgkm(4); MFMA av0xbv(par);
//          vmcnt(6) [10 outstanding -> retires tile t+1]; barrier.
//   P1(t): read av0(t+1), bv(t+1 parity); stage A1,B1(t+3); lgkm(8);
//          MFMA av1xbv(par); barrier.
//   Tail t=70,71 peeled; staging clamped to tile 71 (junk slots never read);
//   epilogue __syncthreads drains remaining gll16s before LDS reuse.
// ws layout:
//   [0,4) dropped | [1024,+50176) sel | [65536,+29491200) xt bf16 [64][30][30][256]
//   [+2359296) wt bf16 pre-swizzled [72*2][256 rows][4 slots][8] (BK=32 blocks)
// ---------------------------------------------------------------------------

typedef __bf16  bf16x8 __attribute__((ext_vector_type(8)));
typedef float   f32x4  __attribute__((ext_vector_type(4)));
typedef unsigned int u32;
typedef unsigned short u16;

#define XT_OFF     65536
#define WT_OFF     (65536 + 29491200)
#define SEL_OFF    1024

__device__ __forceinline__ u16 f2bf(float v) {
    u32 u = __float_as_uint(v);
    u32 r = (u + 0x7FFFu + ((u >> 16) & 1u)) >> 16;
    return (u16)r;
}

__device__ __forceinline__ void gll16(const void* g, void* l) {
    __builtin_amdgcn_global_load_lds(
        (const __attribute__((address_space(1))) u32*)g,
        (__attribute__((address_space(3))) u32*)l, 16, 0, 0);
}

// ---------------- fused prep: xt transform + wt swizzle + mask -------------
__global__ void prep_kernel(const float* __restrict__ x,
                            const float* __restrict__ wl,
                            const float* __restrict__ wp,
                            const float* __restrict__ mu,
                            u16* __restrict__ xt, u16* __restrict__ wt,
                            unsigned char* __restrict__ sel,
                            int* __restrict__ dropped) {
    int b = blockIdx.x, tid = threadIdx.x;
    if (b < 1920) {                                   // ---- xt: 64*30 rows
        int n = b / 30, oh = b % 30;
        u16* row = xt + (size_t)(n * 30 + oh) * 30 * 256;
        if (oh == 0 || oh == 29) {                    // halo rows: full zero
            u32* r32 = (u32*)row;
            #pragma unroll
            for (int i = 0; i < 15; ++i) r32[i * 256 + tid] = 0;
            return;
        }
        int h = oh - 1;
        row[tid] = 0;
        row[29 * 256 + tid] = 0;
        const float* src = x + ((size_t)(n * 256 + tid) * 28 + h) * 28;
        float f[28];
        #pragma unroll
        for (int q = 0; q < 7; ++q) {
            float4 v = *(const float4*)(src + q * 4);
            f[q * 4 + 0] = v.x; f[q * 4 + 1] = v.y;
            f[q * 4 + 2] = v.z; f[q * 4 + 3] = v.w;
        }
        #pragma unroll
        for (int w = 0; w < 28; ++w)
            row[(1 + w) * 256 + tid] = f2bf(f[w]);
    } else if (b < 6528) {                            // ---- wt: BK=32 blocks
        // block bb = t*2 + bn (t 0..71): [row 0..255][ps 0..3][jj 0..7]
        // phys slot ps holds logical channels (ps ^ ((row>>1)&3))*8 + jj
        int gid = (b - 1920) * 256 + tid;             // 1179648 exact
        int bb = gid >> 13;
        int e = gid & 8191;
        int t = bb >> 1, bnn = bb & 1;
        int kk = t >> 3;                              // tap 0..8
        int row = e >> 5, r2 = e & 31;
        int ps = r2 >> 3, jj = r2 & 7;
        int c = (t & 7) * 32 + ((ps ^ ((row >> 1) & 3)) << 3) + jj;
        const float* wsrc = bnn ? wp : wl;
        wt[gid] = f2bf(wsrc[((size_t)row * 256 + c) * 9 + kk]);
    } else {                                          // ---- mask + pooled sel
        int m = (b - 6528) * 256 + tid;               // 196*256 exact
        int n = m / 784, rem = m % 784;
        int h = rem / 28, w = rem % 28;
        const float g = (float)(0.1 / 49.0);
        const float* un = mu + n * 784;
        int p = 0;
        for (int dy = -3; dy <= 3; ++dy) {
            int hh = h + dy;
            if (hh < 0 || hh >= 28) continue;
            for (int dx = -3; dx <= 3; ++dx) {
                int ww = w + dx;
                if (ww < 0 || ww >= 28) continue;
                p |= (un[hh * 28 + ww] < g) ? 1 : 0;
            }
        }
        sel[m] = (unsigned char)p;
        unsigned long long bl = __ballot(p);
        if ((tid & 63) == 0) atomicAdd(dropped, __popcll(bl));
    }
}

// ---------------- implicit-GEMM conv + select + scale ----------------------
__global__ __launch_bounds__(512, 2)
void conv_kernel(const char* __restrict__ xt,    // bf16 padded NHWC (bytes)
                 const char* __restrict__ wt,    // bf16 swizzled blocks (bytes)
                 const unsigned char* __restrict__ sel,
                 const int* __restrict__ dropped,
                 float* __restrict__ out) {
    __shared__ char smem[131072];                 // 4 slots x 32 KB
    const int tid = threadIdx.x;
    const int lb = (blockIdx.x & 7) * 49 + (blockIdx.x >> 3);  // XCD swizzle
    const int bm = lb >> 1;                  // 196 M-tiles of 256 positions
    const int bn = lb & 1;                   // 0 -> a, 1 -> b
    const int lane = tid & 63, wave = tid >> 6;
    const int lane15 = lane & 15, grp = lane >> 4;
    const int wm = wave >> 2, wn = wave & 3; // per-wave 128 x 64 output

    // --- A staging source bases; source-side swizzle folded in ---
    // thread covers row r0 (A0-set) / r0+64 (A1-set), slot = tid&3
    long baseA0, baseA1;
    {
        int i = tid >> 2;
        int r0 = (i & 63) + ((i & 64) << 1);         // {0..63, 128..191}
        int swz = ((tid & 3) ^ ((tid >> 3) & 3)) << 4;
        int m0 = bm * 256 + r0;
        int n0 = m0 / 784, re0 = m0 % 784;
        baseA0 = (long)(((n0 * 30 + re0 / 28 + 1) * 30 + (re0 % 28 + 1)) * 512 + swz);
        int m1 = m0 + 64;
        int n1 = m1 / 784, re1 = m1 % 784;
        baseA1 = (long)(((n1 * 30 + re1 / 28 + 1) * 30 + (re1 % 28 + 1)) * 512 + swz);
    }

    f32x4 acc[8][4];
    #pragma unroll
    for (int i = 0; i < 8; ++i)
        #pragma unroll
        for (int j = 0; j < 4; ++j)
            acc[i][j] = (f32x4){0.f, 0.f, 0.f, 0.f};

    const int so  = (grp ^ ((lane15 >> 1) & 3)) << 4;    // read swizzle
    const int arb = wm * 4096 + (lane15 << 6) + so;      // A within-chunk
    const int brb = wn * 4096 + (lane15 << 6) + so;      // B within-chunk

#define AON(TC) ((long)((TC) >> 3) / 3 * 15360 + (long)(((TC) >> 3) % 3) * 512 \
                 - 15872 + (long)(((TC) & 7) << 6))
#define DS_AV(dst, base, mh) { _Pragma("unroll")                            \
        for (int fm = 0; fm < 4; ++fm)                                      \
            dst[fm] = *(const bf16x8*)((base) + (mh)*8192 + arb + (fm<<10)); }
#define DS_BV(dst, base) { _Pragma("unroll")                                \
        for (int fn = 0; fn < 4; ++fn)                                      \
            dst[fn] = *(const bf16x8*)((base) + 16384 + brb + (fn<<10)); }
#define MM(A0_, AV, BV) { __builtin_amdgcn_s_setprio(1);                    \
        _Pragma("unroll")                                                   \
        for (int fm = 0; fm < 4; ++fm)                                      \
            _Pragma("unroll")                                               \
            for (int fn = 0; fn < 4; ++fn)                                  \
                acc[(A0_)+fm][fn] = __builtin_amdgcn_mfma_f32_16x16x32_bf16( \
                    AV[fm], BV[fn], acc[(A0_)+fm][fn], 0, 0, 0);            \
        __builtin_amdgcn_s_setprio(0); }
#define LGKM(N) { asm volatile("s_waitcnt lgkmcnt(" #N ")" ::: "memory");   \
                  __builtin_amdgcn_sched_barrier(0); }
#define VM(N)   asm volatile("s_waitcnt vmcnt(" #N ")" ::: "memory");
#define BAR     asm volatile("s_barrier" ::: "memory");

    bf16x8 av0[4], av1[4], bv0[4], bv1[4];

    // --- prologue: stage tiles 0,1,2 (order A0,B0,A1,B1 per tile) ---
    #pragma unroll
    for (int tt = 0; tt < 3; ++tt) {
        char* sd = smem + tt * 32768;
        const long ao = AON(tt);
        const char* wb = wt + (size_t)(tt * 2 + bn) * 16384;
        gll16(xt + baseA0 + ao, sd + (tid << 4));
        gll16(wb + (tid << 4), sd + 16384 + (tid << 4));
        gll16(xt + baseA1 + ao, sd + 8192 + (tid << 4));
        gll16(wb + 8192 + (tid << 4), sd + 24576 + (tid << 4));
    }
    VM(8);      // retire tile 0 (12 outstanding -> 8)
    BAR;
    DS_AV(av0, smem, 0);
    DS_BV(bv0, smem);

    for (int u = 0; u < 35; ++u) {
        const int te = 2 * u;
        // ---- tile te (even, bv0) ----
        {
            const char* scur = smem + (te & 3) * 32768;
            char* sdst = smem + ((te + 3) & 3) * 32768;
            int tc = te + 3; if (tc > 71) tc = 71;
            const long aoc = AON(tc);
            const char* wbc = wt + (size_t)(tc * 2 + bn) * 16384;
            // P0
            DS_AV(av1, scur, 1);
            gll16(xt + baseA0 + aoc, sdst + (tid << 4));
            gll16(wbc + (tid << 4), sdst + 16384 + (tid << 4));
            LGKM(4);
            MM(0, av0, bv0);
            VM(6);      // retires tile te+1
            BAR;
            // P1
            const char* snxt = smem + ((te + 1) & 3) * 32768;
            DS_AV(av0, snxt, 0);
            DS_BV(bv1, snxt);
            gll16(xt + baseA1 + aoc, sdst + 8192 + (tid << 4));
            gll16(wbc + 8192 + (tid << 4), sdst + 24576 + (tid << 4));
            LGKM(8);
            MM(4, av1, bv0);
            BAR;
        }
        // ---- tile to = te+1 (odd, bv1) ----
        {
            const int to = te + 1;
            const char* scur = smem + (to & 3) * 32768;
            char* sdst = smem + ((to + 3) & 3) * 32768;
            int tc = to + 3; if (tc > 71) tc = 71;
            const long aoc = AON(tc);
            const char* wbc = wt + (size_t)(tc * 2 + bn) * 16384;
            // P0
            DS_AV(av1, scur, 1);
            gll16(xt + baseA0 + aoc, sdst + (tid << 4));
            gll16(wbc + (tid << 4), sdst + 16384 + (tid << 4));
            LGKM(4);
            MM(0, av0, bv1);
            VM(6);      // retires tile to+1
            BAR;
            // P1
            const char* snxt = smem + ((to + 1) & 3) * 32768;
            DS_AV(av0, snxt, 0);
            DS_BV(bv0, snxt);
            gll16(xt + baseA1 + aoc, sdst + 8192 + (tid << 4));
            gll16(wbc + 8192 + (tid << 4), sdst + 24576 + (tid << 4));
            LGKM(8);
            MM(4, av1, bv1);
            BAR;
        }
    }
    // ---- tail: tiles 70 (bv0), 71 (bv1) ----
    {
        const char* scur = smem + 2 * 32768;           // 70&3
        char* sdst = smem + 1 * 32768;                  // junk slot
        const long aoc = AON(71);
        const char* wbc = wt + (size_t)(71 * 2 + bn) * 16384;
        // P0(70)
        DS_AV(av1, scur, 1);
        gll16(xt + baseA0 + aoc, sdst + (tid << 4));
        gll16(wbc + (tid << 4), sdst + 16384 + (tid << 4));
        LGKM(4);
        MM(0, av0, bv0);
        VM(6);          // retires tile 71 (real, staged at t=68)
        BAR;
        // P1(70)
        const char* snxt = smem + 3 * 32768;            // tile 71
        DS_AV(av0, snxt, 0);
        DS_BV(bv1, snxt);
        gll16(xt + baseA1 + aoc, sdst + 8192 + (tid << 4));
        gll16(wbc + 8192 + (tid << 4), sdst + 24576 + (tid << 4));
        LGKM(8);
        MM(4, av1, bv0);
        BAR;
        // P0(71)
        DS_AV(av1, snxt, 1);
        LGKM(4);
        MM(0, av0, bv1);
        BAR;
        // P1(71)
        LGKM(0);
        MM(4, av1, bv1);
    }

    // --- epilogue: per-wave LDS transpose -> coalesced predicated stores ---
    float scale = 50176.0f / (float)(50176 - *dropped);
    float* ep = (float*)(smem + (wave << 14));   // private [32][65] f32
    __syncthreads();    // full waitcnt drain (incl. junk gll16) + barrier
    #pragma unroll
    for (int rr = 0; rr < 4; ++rr) {
        const int r2 = rr & 1;        // fn pair (32 channels)
        const int mh = rr >> 1;       // m half (64 positions)
        #pragma unroll
        for (int fm2 = 0; fm2 < 4; ++fm2)
            #pragma unroll
            for (int f2 = 0; f2 < 2; ++f2)
                #pragma unroll
                for (int j = 0; j < 4; ++j)
                    ep[(f2 * 16 + lane15) * 65 + fm2 * 16 + grp * 4 + j] =
                        acc[mh * 4 + fm2][r2 * 2 + f2][j];
        __syncthreads();
        {
            int p = bm * 256 + wm * 128 + mh * 64 + lane;
            int n = p / 784, rem = p % 784;
            unsigned char sv = sel[p];
            bool want = bn ? (sv != 0) : (sv == 0);
            size_t ob = (size_t)n * 200704 + rem;
            if (want) {
                #pragma unroll
                for (int ch = 0; ch < 32; ++ch)
                    out[ob + (size_t)(wn * 64 + r2 * 32 + ch) * 784] =
                        ep[ch * 65 + lane] * scale;
            }
        }
        __syncthreads();
    }
#undef AON
#undef DS_AV
#undef DS_BV
#undef MM
#undef LGKM
#undef VM
#undef BAR
}

// ---------------------------------------------------------------------------
extern "C" void kernel_launch(void* const* d_in, const int* in_sizes, int n_in,
                              void* d_out, int out_size, void* d_ws, size_t ws_size,
                              hipStream_t stream) {
    const float* x  = (const float*)d_in[0];
    const float* wl = (const float*)d_in[1];
    const float* wp = (const float*)d_in[2];
    const float* mu = (const float*)d_in[3];
    float* out = (float*)d_out;
    char* ws = (char*)d_ws;

    int* dropped = (int*)ws;
    unsigned char* sel = (unsigned char*)(ws + SEL_OFF);
    u16* xt = (u16*)(ws + XT_OFF);
    u16* wt = (u16*)(ws + WT_OFF);

    hipMemsetAsync(ws, 0, 4, stream);

    prep_kernel<<<6724, 256, 0, stream>>>(x, wl, wp, mu, xt, wt, sel, dropped);
    conv_kernel<<<392, 512, 0, stream>>>((const char*)xt, (const char*)wt,
                                         sel, dropped, out);
}